// Round 7
// baseline (315.923 us; speedup 1.0000x reference)
//
#include <hip/hip_runtime.h>
#include <hip/hip_bf16.h>

using bf16 = __bf16;
typedef __bf16 bf16x8 __attribute__((ext_vector_type(8)));
typedef float f32x4 __attribute__((ext_vector_type(4)));

__device__ __forceinline__ void gload_lds16(const bf16* g, bf16* l) {
  __builtin_amdgcn_global_load_lds(
      (const __attribute__((address_space(1))) void*)g,
      (__attribute__((address_space(3))) void*)l, 16, 0, 0);
}

// fp32 -> bf16, 8 elems/thread
__global__ __launch_bounds__(256) void cvt_f32_bf16(const float* __restrict__ in,
                                                    bf16* __restrict__ out, int n) {
  int i = (blockIdx.x * 256 + threadIdx.x) * 8;
  if (i >= n) return;
  float4 f0 = *(const float4*)&in[i];
  float4 f1 = *(const float4*)&in[i + 4];
  bf16x8 o;
  o[0] = (bf16)f0.x; o[1] = (bf16)f0.y; o[2] = (bf16)f0.z; o[3] = (bf16)f0.w;
  o[4] = (bf16)f1.x; o[5] = (bf16)f1.y; o[6] = (bf16)f1.z; o[7] = (bf16)f1.w;
  *(bf16x8*)&out[i] = o;
}

// frags for one K-tile (BK=32): R[0..7]=A(mi), R[8..11]=B(ni). 12 x b128.
__device__ __forceinline__ void load_frags(const bf16* __restrict__ buf,
                                           int wr, int wc, int lk, int lr,
                                           bf16x8 (&R)[12]) {
#pragma unroll
  for (int mi = 0; mi < 8; ++mi) {
    const int r = wr * 128 + mi * 16 + lr;
    R[mi] = *(const bf16x8*)&buf[r * 32 + ((lk ^ ((r >> 1) & 3)) << 3)];
  }
#pragma unroll
  for (int ni = 0; ni < 4; ++ni) {
    const int r = wc * 64 + ni * 16 + lr;
    R[8 + ni] = *(const bf16x8*)&buf[8192 + r * 32 + ((lk ^ ((r >> 1) & 3)) << 3)];
  }
}

__device__ __forceinline__ void mfma_tile(const bf16x8 (&R)[12], f32x4 (&acc)[8][4]) {
  __builtin_amdgcn_s_setprio(1);
#pragma unroll
  for (int mi = 0; mi < 8; ++mi)
#pragma unroll
    for (int ni = 0; ni < 4; ++ni)
      acc[mi][ni] = __builtin_amdgcn_mfma_f32_16x16x32_bf16(R[mi], R[8 + ni], acc[mi][ni], 0, 0, 0);
  __builtin_amdgcn_s_setprio(0);
}

// C = A @ B^T. 256x256 tile, BK=32, 8 waves (2x4), wave out 128x64.
// K-split software pipeline, COMPILER-SCHEDULED (no sched_barrier, no manual
// lgkmcnt — the compiler emits fine-grained lgkmcnt(N) for ds_read->MFMA and
// can interleave MFMA issue with next-tile read issue; matrix pipe drains
// during read/stage phases). Counted vmcnt kept (compiler can't derive
// global_load_lds->ds_read deps). Race-freedom: reads of buf b complete
// before tile-b's MFMAs issue (auto-waits), which precede the end-of-iter
// barrier, which precedes any re-stage of b (3 tiles later).
// 4-buffer cyclic LDS (32KB/buf). Reg double-buffer R0/R1, unrolled x2.
// Chunk swizzle c ^= ((r>>1)&3) on stage-source + ds_read: 0 bank conflicts.
// EPI 0: bf16 C = scale*acc. EPI 1: bf16 C = exp(scale*acc).
// EPI 2: fp32 C = acc * Inv[row] + Add.
// Requires: M%256==0, N%256==0, K%64==0, K>=256; if gridDim.z>1, nwg%8==0.
template <int EPI>
__global__ __launch_bounds__(512, 2)
void gemm_bt(const bf16* __restrict__ A, const bf16* __restrict__ B,
             void* __restrict__ Cv, const float* __restrict__ Add,
             const float* __restrict__ Inv,
             int K, int lda, int ldb, int ldc,
             long sA, long sB, long sC, long sAdd, float scale) {
  int bx = blockIdx.x, by = blockIdx.y, bz = blockIdx.z;
  if (gridDim.z > 1) {  // XCD chunked swizzle
    const int gx = gridDim.x, gxy = gx * gridDim.y;
    const int nwg = gxy * gridDim.z;
    int lin = bx + gx * by + gxy * bz;
    lin = (lin & 7) * (nwg >> 3) + (lin >> 3);
    bz = lin / gxy; const int rem = lin - bz * gxy;
    by = rem / gx;  bx = rem - by * gx;
  }
  A += (long)bz * sA;
  B += (long)bz * sB;
  const int tid = threadIdx.x;
  const int lane = tid & 63;
  const int wave = tid >> 6;
  const int wr = wave >> 2;        // 0..1
  const int wc = wave & 3;         // 0..3
  const long brow = (long)bx * 256;
  const long bcol = (long)by * 256;

  __shared__ bf16 lds[4][16384];   // 4 bufs x 32KB: A[256][32], B[256][32]

  f32x4 acc[8][4] = {};

  // staging: 4 gloads/thread/tile. rows srow & srow+128, dest chunk tid&3,
  // source chunk swizzled by ((srow>>1)&3) (same for row+128).
  const int srow = tid >> 2;                      // 0..127
  const int scg  = (tid & 3) ^ ((srow >> 1) & 3);
  const bf16* gA = A + (brow + srow) * (long)lda + scg * 8;
  const bf16* gB = B + (bcol + srow) * (long)ldb + scg * 8;
  const long a128 = (long)lda << 7;
  const long b128 = (long)ldb << 7;

  const int nk = K >> 5;           // even (K%64==0)

  auto stage = [&](int t) {
    bf16* buf = (bf16*)lds[t & 3];
    const bf16* a = gA + (long)t * 32;
    const bf16* b = gB + (long)t * 32;
    gload_lds16(a,        buf + tid * 8);
    gload_lds16(a + a128, buf + 4096 + tid * 8);
    gload_lds16(b,        buf + 8192 + tid * 8);
    gload_lds16(b + b128, buf + 12288 + tid * 8);
  };

  const int lk = lane >> 4;   // 0..3 (k-chunk)
  const int lr = lane & 15;   // row-within-frag

  // prologue: stage tiles 0,1,2; certify 0,1 (leave tile2's 4 in flight)
  stage(0); stage(1); stage(2);
  asm volatile("s_waitcnt vmcnt(4)" ::: "memory");
  __builtin_amdgcn_s_barrier();

  bf16x8 R0[12], R1[12];
  load_frags((const bf16*)lds[0], wr, wc, lk, lr, R0);

  for (int t = 0; t < nk; t += 2) {
    // ---- even tile t: compute R0, prefetch R1 = frags(t+1)
    load_frags((const bf16*)lds[(t + 1) & 3], wr, wc, lk, lr, R1);
    if (t + 3 < nk) stage(t + 3);
    mfma_tile(R0, acc);            // compiler auto-waits exact R0 lgkm deps
    if (t + 3 < nk) { asm volatile("s_waitcnt vmcnt(4)" ::: "memory"); }
    else            { asm volatile("s_waitcnt vmcnt(0)" ::: "memory"); }
    __builtin_amdgcn_s_barrier();
    // ---- odd tile t+1: compute R1, prefetch R0 = frags(t+2)
    if (t + 2 < nk) load_frags((const bf16*)lds[(t + 2) & 3], wr, wc, lk, lr, R0);
    if (t + 4 < nk) stage(t + 4);
    mfma_tile(R1, acc);
    if (t + 4 < nk) { asm volatile("s_waitcnt vmcnt(4)" ::: "memory"); }
    else            { asm volatile("s_waitcnt vmcnt(0)" ::: "memory"); }
    __builtin_amdgcn_s_barrier();
  }

  // epilogue. C/D layout: col = lane&15, row = (lane>>4)*4 + j
  const int or0 = wr * 128 + ((lane >> 4) << 2);
  const int oc0 = wc * 64 + (lane & 15);
#pragma unroll
  for (int mi = 0; mi < 8; ++mi) {
#pragma unroll
    for (int ni = 0; ni < 4; ++ni) {
#pragma unroll
      for (int j = 0; j < 4; ++j) {
        const long row = brow + or0 + mi * 16 + j;
        const long col = bcol + oc0 + ni * 16;
        if constexpr (EPI == 0) {
          bf16* C = (bf16*)Cv + (long)bz * sC;
          C[row * ldc + col] = (bf16)(acc[mi][ni][j] * scale);
        } else if constexpr (EPI == 1) {
          bf16* C = (bf16*)Cv + (long)bz * sC;
          C[row * ldc + col] = (bf16)__expf(acc[mi][ni][j] * scale);
        } else {
          float* C = (float*)Cv + (long)bz * sC;
          const float* Ad = Add + (long)bz * sAdd;
          const float* iv = Inv + (long)bz * 2048;
          C[row * ldc + col] = acc[mi][ni][j] * iv[row] + Ad[row * ldc + col];
        }
      }
    }
  }
}

// per-row sum of exp-scores E (rows of 2048 bf16) -> inv[row] = 1/sum
__global__ __launch_bounds__(256) void rowsum_inv(const bf16* __restrict__ E,
                                                  float* __restrict__ inv) {
  const long row = blockIdx.x;
  const bf16* p = E + row * 2048;
  const int tid = threadIdx.x;
  bf16x8 v = *(const bf16x8*)&p[tid * 8];
  float s = 0.f;
#pragma unroll
  for (int i = 0; i < 8; ++i) s += (float)v[i];
#pragma unroll
  for (int off = 32; off > 0; off >>= 1) s += __shfl_xor(s, off, 64);
  __shared__ float red[4];
  if ((tid & 63) == 0) red[tid >> 6] = s;
  __syncthreads();
  if (tid == 0) inv[row] = 1.0f / (red[0] + red[1] + red[2] + red[3]);
}

extern "C" void kernel_launch(void* const* d_in, const int* in_sizes, int n_in,
                              void* d_out, int out_size, void* d_ws, size_t ws_size,
                              hipStream_t stream) {
  const float* q_in = (const float*)d_in[0];  // (8,2048,1024)
  const float* k_in = (const float*)d_in[1];  // (8,2048,1024)
  const float* Wq   = (const float*)d_in[2];  // (1024,1024)
  const float* Wk   = (const float*)d_in[3];
  const float* Wv   = (const float*)d_in[4];
  float* out = (float*)d_out;
  char* ws = (char*)d_ws;

  bf16* qb  = (bf16*)(ws);                 // 33,554,432 B
  bf16* kb  = (bf16*)(ws + 33554432);      // 33,554,432 B
  bf16* S   = (bf16*)(ws);                 // 67,108,864 B (reuse of qb+kb)
  bf16* Wqb = (bf16*)(ws + 67108864);
  float* inv = (float*)(ws + 67108864);    // 64 KB, reuses Wqb after proj Q
  bf16* Wkb = (bf16*)(ws + 69206016);
  bf16* Wvb = (bf16*)(ws + 71303168);
  bf16* Qp  = (bf16*)(ws + 73400320);
  bf16* Kp  = (bf16*)(ws + 106954752);
  bf16* Vpt = (bf16*)(ws + 140509184);     // (b,1024,2048) = Vp^T per batch

  cvt_f32_bf16<<<8192, 256, 0, stream>>>(q_in, qb, 16777216);
  cvt_f32_bf16<<<8192, 256, 0, stream>>>(k_in, kb, 16777216);
  cvt_f32_bf16<<<512, 256, 0, stream>>>(Wq, Wqb, 1048576);
  cvt_f32_bf16<<<512, 256, 0, stream>>>(Wk, Wkb, 1048576);
  cvt_f32_bf16<<<512, 256, 0, stream>>>(Wv, Wvb, 1048576);

  // Qp = qb @ Wq^T  (M=16384, N=1024, K=1024)
  gemm_bt<0><<<dim3(64, 4, 1), 512, 0, stream>>>(
      qb, Wqb, Qp, nullptr, nullptr, 1024, 1024, 1024, 1024, 0, 0, 0, 0, 1.0f);
  // Kp = kb @ Wk^T
  gemm_bt<0><<<dim3(64, 4, 1), 512, 0, stream>>>(
      kb, Wkb, Kp, nullptr, nullptr, 1024, 1024, 1024, 1024, 0, 0, 0, 0, 1.0f);
  // Vpt[b] = Wv @ qb[b]^T  (M=1024, N=2048, K=1024)
  gemm_bt<0><<<dim3(4, 8, 8), 512, 0, stream>>>(
      Wvb, qb, Vpt, nullptr, nullptr, 1024, 1024, 1024, 2048,
      0L, 2097152L, 2097152L, 0L, 1.0f);

  // S[b] = exp(Kp[b] @ Qp[b]^T / 32)  (M=2048, N=2048, K=1024) — max-free
  gemm_bt<1><<<dim3(8, 8, 8), 512, 0, stream>>>(
      Kp, Qp, S, nullptr, nullptr, 1024, 1024, 1024, 2048,
      2097152L, 2097152L, 4194304L, 0L, 0.03125f);

  // inv[row] = 1 / rowsum(S)
  rowsum_inv<<<16384, 256, 0, stream>>>(S, inv);

  // out[b] = (S[b] @ Vpt[b]') * inv + key_input[b]  (M=2048, N=1024, K=2048)
  gemm_bt<2><<<dim3(8, 4, 8), 512, 0, stream>>>(
      S, Vpt, out, k_in, inv, 2048, 2048, 2048, 1024,
      4194304L, 2097152L, 2097152L, 2097152L, 1.0f);
}